// Round 1
// baseline (421.741 us; speedup 1.0000x reference)
//
#include <hip/hip_runtime.h>

typedef __attribute__((ext_vector_type(4))) float f32x4;
typedef __attribute__((ext_vector_type(8))) short s16x8;
typedef __attribute__((ext_vector_type(8))) unsigned short u16x8;

#define AS1 __attribute__((address_space(1)))
#define AS3 __attribute__((address_space(3)))

constexpr int MDIM = 8192;   // batch
constexpr int NDIM = 4096;   // out features
constexpr int KDIM = 4096;   // in features

__device__ __forceinline__ unsigned short f2bf(float f) {
  unsigned int u = __float_as_uint(f);
  u += 0x7fffu + ((u >> 16) & 1u);   // round-to-nearest-even
  return (unsigned short)(u >> 16);
}

__device__ __forceinline__ void gld_lds16(const unsigned short* g, unsigned short* l) {
  __builtin_amdgcn_global_load_lds((const AS1 void*)g, (AS3 void*)l, 16, 0, 0);
}

// ---- x f32 -> bf16 ----
__global__ void cvt_x_kernel(const float* __restrict__ x, unsigned short* __restrict__ xb) {
  const int n8 = MDIM * KDIM / 8;
  for (int i = blockIdx.x * blockDim.x + threadIdx.x; i < n8; i += gridDim.x * blockDim.x) {
    const float4* p = (const float4*)x + 2 * (size_t)i;
    float4 v0 = p[0], v1 = p[1];
    u16x8 r;
    r[0] = f2bf(v0.x); r[1] = f2bf(v0.y); r[2] = f2bf(v0.z); r[3] = f2bf(v0.w);
    r[4] = f2bf(v1.x); r[5] = f2bf(v1.y); r[6] = f2bf(v1.z); r[7] = f2bf(v1.w);
    *((u16x8*)xb + i) = r;
  }
}

// ---- W[o][k] = params[4095 - o + k], as bf16 [NDIM][KDIM] ----
__global__ void build_w_kernel(const float* __restrict__ params, unsigned short* __restrict__ wb) {
  const int n8 = NDIM * KDIM / 8;
  for (int i = blockIdx.x * blockDim.x + threadIdx.x; i < n8; i += gridDim.x * blockDim.x) {
    int o = i >> 9;              // / (4096/8)
    int k0 = (i & 511) << 3;
    const float* p = params + (NDIM - 1 - o + k0);
    u16x8 r;
#pragma unroll
    for (int e = 0; e < 8; ++e) r[e] = f2bf(p[e]);
    *((u16x8*)wb + i) = r;
  }
}

// ---- bf16 GEMM: C = A * Bw^T + bias, A[M][K], Bw[N][K] row-major ----
__global__ __launch_bounds__(256) void toep_gemm(
    const unsigned short* __restrict__ A,
    const unsigned short* __restrict__ Bw,
    const float* __restrict__ bias,
    float* __restrict__ C)
{
  constexpr int BM = 128, BN = 128, BK = 32;
  constexpr int NBM = MDIM / BM;   // 64
  constexpr int NBN = NDIM / BN;   // 32
  __shared__ unsigned short sA[2][BM * BK];
  __shared__ unsigned short sB[2][BN * BK];

  int bid = (int)blockIdx.x;
  constexpr int NWG = NBM * NBN;   // 2048, divisible by 8
  int swz = (bid & 7) * (NWG >> 3) + (bid >> 3);
  int bm = swz / NBN, bn = swz % NBN;   // 32 consecutive swz share one A-panel (1MB, L2-fit)
  int m0 = bm * BM, n0 = bn * BN;

  int t = (int)threadIdx.x;
  int lane = t & 63, wid = t >> 6;

  // staging: tile flat elem = r*2048 + 8t ; row = r*64 + t/4 ; k = (t%4)*8
  const unsigned short* gA0 = A + (size_t)(m0 + (t >> 2)) * KDIM + (t & 3) * 8;
  const unsigned short* gB0 = Bw + (size_t)(n0 + (t >> 2)) * KDIM + (t & 3) * 8;
  const unsigned short* gA1 = gA0 + (size_t)64 * KDIM;
  const unsigned short* gB1 = gB0 + (size_t)64 * KDIM;

  int wm = wid >> 1, wn = wid & 1;    // 2x2 wave grid, 64x64 per wave
  int lr = lane & 15, lk = lane >> 4;

  f32x4 acc[4][4];
#pragma unroll
  for (int i = 0; i < 4; ++i)
#pragma unroll
    for (int j = 0; j < 4; ++j) acc[i][j] = (f32x4){0.f, 0.f, 0.f, 0.f};

  // prologue: stage tile 0 into buf 0
  gld_lds16(gA0, &sA[0][8 * t]);
  gld_lds16(gA1, &sA[0][2048 + 8 * t]);
  gld_lds16(gB0, &sB[0][8 * t]);
  gld_lds16(gB1, &sB[0][2048 + 8 * t]);

  constexpr int NKT = KDIM / BK;   // 128
  for (int kt = 0; kt < NKT; ++kt) {
    int cur = kt & 1;
    __syncthreads();   // drains vmcnt: buf[cur] staged, buf[cur^1] free
    if (kt + 1 < NKT) {
      int ko = (kt + 1) * BK;
      int nxt = cur ^ 1;
      gld_lds16(gA0 + ko, &sA[nxt][8 * t]);
      gld_lds16(gA1 + ko, &sA[nxt][2048 + 8 * t]);
      gld_lds16(gB0 + ko, &sB[nxt][8 * t]);
      gld_lds16(gB1 + ko, &sB[nxt][2048 + 8 * t]);
    }
    const unsigned short* pa = &sA[cur][(wm * 64 + lr) * BK + lk * 8];
    const unsigned short* pb = &sB[cur][(wn * 64 + lr) * BK + lk * 8];
    s16x8 a[4], b[4];
#pragma unroll
    for (int i = 0; i < 4; ++i) a[i] = *(const s16x8*)(pa + i * 16 * BK);
#pragma unroll
    for (int i = 0; i < 4; ++i) b[i] = *(const s16x8*)(pb + i * 16 * BK);
#pragma unroll
    for (int mi = 0; mi < 4; ++mi)
#pragma unroll
      for (int ni = 0; ni < 4; ++ni)
        acc[mi][ni] = __builtin_amdgcn_mfma_f32_16x16x32_bf16(a[mi], b[ni], acc[mi][ni], 0, 0, 0);
  }

  // epilogue: D col = lane&15, row = (lane>>4)*4 + reg
  int colb = n0 + wn * 64 + lr;
  float bv[4];
#pragma unroll
  for (int ni = 0; ni < 4; ++ni) bv[ni] = bias[colb + ni * 16];
#pragma unroll
  for (int mi = 0; mi < 4; ++mi) {
    int rowb = m0 + wm * 64 + mi * 16 + lk * 4;
#pragma unroll
    for (int ni = 0; ni < 4; ++ni) {
      int col = colb + ni * 16;
#pragma unroll
      for (int r = 0; r < 4; ++r)
        C[(size_t)(rowb + r) * NDIM + col] = acc[mi][ni][r] + bv[ni];
    }
  }
}

// ---- exact-f32 fallback (used only if ws too small) ----
__global__ __launch_bounds__(256) void toep_f32_fallback(
    const float* __restrict__ X, const float* __restrict__ P,
    const float* __restrict__ bias, float* __restrict__ C)
{
  constexpr int TM = 64, TN = 64, TK = 32;
  __shared__ float xs[TM][TK + 1];
  __shared__ float win[TN + TK];   // 95 used
  int bm = blockIdx.x / (NDIM / TN);
  int bn = blockIdx.x % (NDIM / TN);
  int m0 = bm * TM, n0 = bn * TN;
  int t = (int)threadIdx.x;
  int tx = t & 15, ty = t >> 4;
  float acc[4][4] = {};
  for (int k0 = 0; k0 < KDIM; k0 += TK) {
    __syncthreads();
    for (int i = t; i < TM * TK; i += 256) {
      int r = i >> 5, c = i & 31;
      xs[r][c] = X[(size_t)(m0 + r) * KDIM + k0 + c];
    }
    if (t < TN + TK - 1) win[t] = P[(NDIM - 1) - n0 - (TN - 1) + k0 + t];
    __syncthreads();
    for (int kk = 0; kk < TK; ++kk) {
      float xv[4];
#pragma unroll
      for (int i = 0; i < 4; ++i) xv[i] = xs[ty * 4 + i][kk];
#pragma unroll
      for (int j = 0; j < 4; ++j) {
        float wv = win[kk + (TN - 1) - (tx * 4 + j)];
#pragma unroll
        for (int i = 0; i < 4; ++i) acc[i][j] += xv[i] * wv;
      }
    }
  }
#pragma unroll
  for (int i = 0; i < 4; ++i)
#pragma unroll
    for (int j = 0; j < 4; ++j)
      C[(size_t)(m0 + ty * 4 + i) * NDIM + n0 + tx * 4 + j] = acc[i][j] + bias[n0 + tx * 4 + j];
}

extern "C" void kernel_launch(void* const* d_in, const int* in_sizes, int n_in,
                              void* d_out, int out_size, void* d_ws, size_t ws_size,
                              hipStream_t stream) {
  const float* x = (const float*)d_in[0];
  const float* params = (const float*)d_in[1];
  const float* bias = (const float*)d_in[2];
  float* out = (float*)d_out;

  const size_t need = (size_t)MDIM * KDIM * 2 + (size_t)NDIM * KDIM * 2;  // 96 MiB
  if (ws_size >= need) {
    unsigned short* xb = (unsigned short*)d_ws;
    unsigned short* wb = xb + (size_t)MDIM * KDIM;
    cvt_x_kernel<<<2048, 256, 0, stream>>>(x, xb);
    build_w_kernel<<<2048, 256, 0, stream>>>(params, wb);
    toep_gemm<<<(MDIM / 128) * (NDIM / 128), 256, 0, stream>>>(xb, wb, bias, out);
  } else {
    toep_f32_fallback<<<(MDIM / 64) * (NDIM / 64), 256, 0, stream>>>(x, params, bias, out);
  }
}

// Round 2
// 304.298 us; speedup vs baseline: 1.3859x; 1.3859x over previous
//
#include <hip/hip_runtime.h>

typedef __attribute__((ext_vector_type(4))) float f32x4;
typedef __attribute__((ext_vector_type(8))) short s16x8;
typedef __attribute__((ext_vector_type(8))) unsigned short u16x8;

#define AS1 __attribute__((address_space(1)))
#define AS3 __attribute__((address_space(3)))

constexpr int MDIM = 8192;   // batch
constexpr int NDIM = 4096;   // out features
constexpr int KDIM = 4096;   // in features

constexpr int BM = 256, BN = 256, BK = 64;
constexpr int NKT = KDIM / BK;   // 64

__device__ __forceinline__ unsigned short f2bf(float f) {
  unsigned int u = __float_as_uint(f);
  u += 0x7fffu + ((u >> 16) & 1u);   // round-to-nearest-even
  return (unsigned short)(u >> 16);
}

__device__ __forceinline__ void gld_lds16(const unsigned short* g, unsigned short* l) {
  __builtin_amdgcn_global_load_lds((const AS1 void*)g, (AS3 void*)l, 16, 0, 0);
}

// ---- x f32 -> bf16 ----
__global__ void cvt_x_kernel(const float* __restrict__ x, unsigned short* __restrict__ xb) {
  const int n8 = MDIM * KDIM / 8;
  for (int i = blockIdx.x * blockDim.x + threadIdx.x; i < n8; i += gridDim.x * blockDim.x) {
    const float4* p = (const float4*)x + 2 * (size_t)i;
    float4 v0 = p[0], v1 = p[1];
    u16x8 r;
    r[0] = f2bf(v0.x); r[1] = f2bf(v0.y); r[2] = f2bf(v0.z); r[3] = f2bf(v0.w);
    r[4] = f2bf(v1.x); r[5] = f2bf(v1.y); r[6] = f2bf(v1.z); r[7] = f2bf(v1.w);
    *((u16x8*)xb + i) = r;
  }
}

// ---- W[o][k] = params[4095 - o + k], as bf16 [NDIM][KDIM] ----
__global__ void build_w_kernel(const float* __restrict__ params, unsigned short* __restrict__ wb) {
  const int n8 = NDIM * KDIM / 8;
  for (int i = blockIdx.x * blockDim.x + threadIdx.x; i < n8; i += gridDim.x * blockDim.x) {
    int o = i >> 9;
    int k0 = (i & 511) << 3;
    const float* p = params + (NDIM - 1 - o + k0);
    u16x8 r;
#pragma unroll
    for (int e = 0; e < 8; ++e) r[e] = f2bf(p[e]);
    *((u16x8*)wb + i) = r;
  }
}

// ================= 256x256 8-phase bf16 GEMM =================
// C = A * Bw^T + bias ; A[M][K], Bw[N][K] row-major bf16, C f32.
// LDS tile [256][64] bf16, XOR-swizzle col ^= (row&7)<<3 (elements).
// Staged via global_load_lds with pre-swizzled global source (linear LDS dest).
__global__ __launch_bounds__(512, 2) void toep_gemm8p(
    const unsigned short* __restrict__ A,
    const unsigned short* __restrict__ Bw,
    const float* __restrict__ bias,
    float* __restrict__ C)
{
  __shared__ unsigned short sA[2][BM * BK];   // 64 KiB
  __shared__ unsigned short sB[2][BN * BK];   // 64 KiB

  constexpr int NBM = MDIM / BM;   // 32
  constexpr int NBN = NDIM / BN;   // 16
  constexpr int NWG = NBM * NBN;   // 512 (divisible by 8)
  int bid = (int)blockIdx.x;
  int swz = (bid & 7) * (NWG >> 3) + (bid >> 3);   // bijective: NWG % 8 == 0
  int bm = swz / NBN, bn = swz % NBN;              // 16 consecutive share A-panel (2MB, L2-fit)
  int m0 = bm * BM, n0 = bn * BN;

  int t = (int)threadIdx.x;
  int lane = t & 63, wid = t >> 6;
  int wm = wid >> 2, wn = wid & 3;     // 2 (M) x 4 (N) wave grid; 128x64 per wave
  int lr = lane & 15, lk = lane >> 4;

  // --- staging addresses: dest linear t*16B, source col pre-swizzled ---
  int scol = (((t & 7) ^ ((t >> 3) & 7)) << 3);
  const unsigned short* gA = A + (size_t)(m0 + (t >> 3)) * KDIM + scol;
  const unsigned short* gB = Bw + (size_t)(n0 + (t >> 3)) * KDIM + scol;

#define STG_A(c, kt, R0) gld_lds16(gA + (size_t)(R0) * KDIM + (kt) * 64, &sA[c][(R0) * 64 + t * 8])
#define STG_B(c, kt, R0) gld_lds16(gB + (size_t)(R0) * KDIM + (kt) * 64, &sB[c][(R0) * 64 + t * 8])

  // --- ds_read fragment addressing (swizzled) ---
  int aswz = (lr & 7) << 3;
  int c0 = (lk * 8) ^ aswz;          // ks=0 physical col (elements)
  int c1 = (32 + lk * 8) ^ aswz;     // ks=1

  s16x8 av[4][2], bv[2][2];
  f32x4 acc[8][4];
#pragma unroll
  for (int i = 0; i < 8; ++i)
#pragma unroll
    for (int j = 0; j < 4; ++j) acc[i][j] = (f32x4){0.f, 0.f, 0.f, 0.f};

#define LDA_SUB(c, msub) do { \
  _Pragma("unroll") \
  for (int mi = 0; mi < 4; ++mi) { \
    const unsigned short* p_ = &sA[c][(wm * 128 + (msub) * 64 + mi * 16 + lr) * 64]; \
    av[mi][0] = *(const s16x8*)(p_ + c0); \
    av[mi][1] = *(const s16x8*)(p_ + c1); \
  } } while (0)

#define LDB_SUB(c, nsub) do { \
  _Pragma("unroll") \
  for (int ni = 0; ni < 2; ++ni) { \
    const unsigned short* p_ = &sB[c][(wn * 64 + (nsub) * 32 + ni * 16 + lr) * 64]; \
    bv[ni][0] = *(const s16x8*)(p_ + c0); \
    bv[ni][1] = *(const s16x8*)(p_ + c1); \
  } } while (0)

#define MMA_Q(msub, nsub) do { \
  __builtin_amdgcn_s_setprio(1); \
  _Pragma("unroll") \
  for (int mi = 0; mi < 4; ++mi) \
    _Pragma("unroll") \
    for (int ni = 0; ni < 2; ++ni) { \
      acc[(msub) * 4 + mi][(nsub) * 2 + ni] = __builtin_amdgcn_mfma_f32_16x16x32_bf16( \
          av[mi][0], bv[ni][0], acc[(msub) * 4 + mi][(nsub) * 2 + ni], 0, 0, 0); \
      acc[(msub) * 4 + mi][(nsub) * 2 + ni] = __builtin_amdgcn_mfma_f32_16x16x32_bf16( \
          av[mi][1], bv[ni][1], acc[(msub) * 4 + mi][(nsub) * 2 + ni], 0, 0, 0); \
    } \
  __builtin_amdgcn_s_setprio(0); \
} while (0)

  // Prologue: stage tile 0 into buf0 in FIFO-need order, leave last 2 A-loads in flight.
  STG_B(0, 0, 0); STG_B(0, 0, 64); STG_B(0, 0, 128); STG_B(0, 0, 192);
  STG_A(0, 0, 0); STG_A(0, 0, 128); STG_A(0, 0, 64); STG_A(0, 0, 192);
  asm volatile("s_waitcnt vmcnt(2)" ::: "memory");
  __builtin_amdgcn_s_barrier();

  // Group: 4 phases for tile kt in buf c; stages tile kt+1 into buf c^1.
  // Stage FIFO: B[0],B[64] | B[128],B[192] | A[0],A[128] | A[64],A[192]
  // Needs(next group): P1 <- loads 1..6 ; P3 <- loads 7,8.
#define GROUP(c, kt) do { \
  const bool st_ = (kt) + 1 < NKT; \
  /* P1: quadrant (m0,n0) */ \
  LDA_SUB(c, 0); LDB_SUB(c, 0); \
  if (st_) { STG_B((c) ^ 1, (kt) + 1, 0); STG_B((c) ^ 1, (kt) + 1, 64); } \
  __builtin_amdgcn_s_barrier(); \
  asm volatile("s_waitcnt lgkmcnt(0)"); \
  MMA_Q(0, 0); \
  __builtin_amdgcn_s_barrier(); \
  /* P2: quadrant (m0,n1) */ \
  LDB_SUB(c, 1); \
  if (st_) { STG_B((c) ^ 1, (kt) + 1, 128); STG_B((c) ^ 1, (kt) + 1, 192); } \
  __builtin_amdgcn_s_barrier(); \
  asm volatile("s_waitcnt lgkmcnt(0)"); \
  MMA_Q(0, 1); \
  if (st_) { asm volatile("s_waitcnt vmcnt(4)" ::: "memory"); } \
  else     { asm volatile("s_waitcnt vmcnt(0)" ::: "memory"); } \
  __builtin_amdgcn_s_barrier(); \
  /* P3: quadrant (m1,n1) — A loads 7,8 of THIS tile now arrived */ \
  LDA_SUB(c, 1); \
  if (st_) { STG_A((c) ^ 1, (kt) + 1, 0); STG_A((c) ^ 1, (kt) + 1, 128); } \
  __builtin_amdgcn_s_barrier(); \
  asm volatile("s_waitcnt lgkmcnt(0)"); \
  MMA_Q(1, 1); \
  __builtin_amdgcn_s_barrier(); \
  /* P4: quadrant (m1,n0) */ \
  LDB_SUB(c, 0); \
  if (st_) { STG_A((c) ^ 1, (kt) + 1, 64); STG_A((c) ^ 1, (kt) + 1, 192); } \
  __builtin_amdgcn_s_barrier(); \
  asm volatile("s_waitcnt lgkmcnt(0)"); \
  MMA_Q(1, 0); \
  asm volatile("s_waitcnt vmcnt(2)" ::: "memory"); \
  __builtin_amdgcn_s_barrier(); \
} while (0)

  for (int kt = 0; kt < NKT; kt += 2) {
    GROUP(0, kt);
    GROUP(1, kt + 1);
  }

  // Epilogue: C/D layout col = lane&15, row = (lane>>4)*4 + reg
  float bvv[4];
#pragma unroll
  for (int fn = 0; fn < 4; ++fn) bvv[fn] = bias[n0 + wn * 64 + fn * 16 + lr];
#pragma unroll
  for (int fm = 0; fm < 8; ++fm) {
    int row0 = m0 + wm * 128 + fm * 16 + lk * 4;
#pragma unroll
    for (int fn = 0; fn < 4; ++fn) {
      int col = n0 + wn * 64 + fn * 16 + lr;
#pragma unroll
      for (int r = 0; r < 4; ++r)
        C[(size_t)(row0 + r) * NDIM + col] = acc[fm][fn][r] + bvv[fn];
    }
  }
#undef GROUP
#undef MMA_Q
#undef LDB_SUB
#undef LDA_SUB
#undef STG_A
#undef STG_B
}

// ---- exact-f32 fallback (used only if ws too small) ----
__global__ __launch_bounds__(256) void toep_f32_fallback(
    const float* __restrict__ X, const float* __restrict__ P,
    const float* __restrict__ bias, float* __restrict__ C)
{
  constexpr int TM = 64, TN = 64, TK = 32;
  __shared__ float xs[TM][TK + 1];
  __shared__ float win[TN + TK];
  int bm = blockIdx.x / (NDIM / TN);
  int bn = blockIdx.x % (NDIM / TN);
  int m0 = bm * TM, n0 = bn * TN;
  int t = (int)threadIdx.x;
  int tx = t & 15, ty = t >> 4;
  float acc[4][4] = {};
  for (int k0 = 0; k0 < KDIM; k0 += TK) {
    __syncthreads();
    for (int i = t; i < TM * TK; i += 256) {
      int r = i >> 5, c = i & 31;
      xs[r][c] = X[(size_t)(m0 + r) * KDIM + k0 + c];
    }
    if (t < TN + TK - 1) win[t] = P[(NDIM - 1) - n0 - (TN - 1) + k0 + t];
    __syncthreads();
    for (int kk = 0; kk < TK; ++kk) {
      float xv[4];
#pragma unroll
      for (int i = 0; i < 4; ++i) xv[i] = xs[ty * 4 + i][kk];
#pragma unroll
      for (int j = 0; j < 4; ++j) {
        float wv = win[kk + (TN - 1) - (tx * 4 + j)];
#pragma unroll
        for (int i = 0; i < 4; ++i) acc[i][j] += xv[i] * wv;
      }
    }
  }
#pragma unroll
  for (int i = 0; i < 4; ++i)
#pragma unroll
    for (int j = 0; j < 4; ++j)
      C[(size_t)(m0 + ty * 4 + i) * KDIM + n0 + tx * 4 + j] = acc[i][j] + bias[n0 + tx * 4 + j];
}

extern "C" void kernel_launch(void* const* d_in, const int* in_sizes, int n_in,
                              void* d_out, int out_size, void* d_ws, size_t ws_size,
                              hipStream_t stream) {
  const float* x = (const float*)d_in[0];
  const float* params = (const float*)d_in[1];
  const float* bias = (const float*)d_in[2];
  float* out = (float*)d_out;

  const size_t need = (size_t)MDIM * KDIM * 2 + (size_t)NDIM * KDIM * 2;  // 96 MiB
  if (ws_size >= need) {
    unsigned short* xb = (unsigned short*)d_ws;
    unsigned short* wb = xb + (size_t)MDIM * KDIM;
    cvt_x_kernel<<<2048, 256, 0, stream>>>(x, xb);
    build_w_kernel<<<2048, 256, 0, stream>>>(params, wb);
    toep_gemm8p<<<(MDIM / BM) * (NDIM / BN), 512, 0, stream>>>(xb, wb, bias, out);
  } else {
    toep_f32_fallback<<<(MDIM / 64) * (NDIM / 64), 256, 0, stream>>>(x, params, bias, out);
  }
}